// Round 12
// baseline (205.294 us; speedup 1.0000x reference)
//
#include <hip/hip_runtime.h>
#include <stdint.h>

typedef __attribute__((ext_vector_type(8))) short short8v;    // 8 x bf16 (raw bits)
typedef __attribute__((ext_vector_type(4))) short short4v;    // 4 x bf16
typedef __attribute__((ext_vector_type(4))) float float4v;    // MFMA C/D
typedef __attribute__((ext_vector_type(4))) unsigned short ushort4v;
typedef __attribute__((ext_vector_type(4))) float floatvec4;
typedef __attribute__((ext_vector_type(2))) unsigned int uint2v;
typedef __attribute__((ext_vector_type(4))) unsigned int uint4v;
typedef __attribute__((ext_vector_type(8))) unsigned short ushort8v;

#define DEVI __device__ __forceinline__

// fp32 -> bf16 round-to-nearest-even (finite inputs only)
DEVI unsigned short f2bf(float f) {
    unsigned int u = __builtin_bit_cast(unsigned int, f);
    u += 0x7FFFu + ((u >> 16) & 1u);
    return (unsigned short)(u >> 16);
}

// pack 2 fp32 -> 2 bf16 in one u32 (low = a)
DEVI unsigned int pk2bf(float a, float b) {
#if defined(__has_builtin) && __has_builtin(__builtin_amdgcn_cvt_pk_bf16_f32)
    auto r = __builtin_amdgcn_cvt_pk_bf16_f32(a, b);
    unsigned int u;
    __builtin_memcpy(&u, &r, 4);
    return u;
#else
    return (unsigned int)f2bf(a) | ((unsigned int)f2bf(b) << 16);
#endif
}

DEVI float ex2(float x) {
#if defined(__has_builtin) && __has_builtin(__builtin_amdgcn_exp2f)
    return __builtin_amdgcn_exp2f(x);
#else
    return __builtin_exp2f(x);
#endif
}

// permlane swaps (hardware-verified lane mapping, R1/R2/R10/R11 passed):
// P32: D[32:63] <-> S[0:31].  P16: D[16:31]<->S[0:15], D[48:63]<->S[32:47].
DEVI uint2v pl32swap(unsigned int d, unsigned int s) {
#if defined(__has_builtin) && __has_builtin(__builtin_amdgcn_permlane32_swap)
    return __builtin_amdgcn_permlane32_swap(d, s, false, false);
#else
    const int hi = (int)(threadIdx.x & 32);
    unsigned int dp = __shfl_xor(d, 32), sp = __shfl_xor(s, 32);
    return (uint2v){hi ? sp : d, hi ? s : dp};
#endif
}
DEVI uint2v pl16swap(unsigned int d, unsigned int s) {
#if defined(__has_builtin) && __has_builtin(__builtin_amdgcn_permlane16_swap)
    return __builtin_amdgcn_permlane16_swap(d, s, false, false);
#else
    const int lo = (int)(threadIdx.x & 16);
    unsigned int dp = __shfl_xor(d, 16), sp = __shfl_xor(s, 16);
    return (uint2v){lo ? sp : d, lo ? s : dp};
#endif
}

typedef __attribute__((address_space(1))) void GV;
typedef __attribute__((address_space(3))) void LV;
// async global->LDS, 16B per lane; LDS dest = wave-uniform base + lane*16
DEVI void gl2lds16(const void* g, void* l) {
    __builtin_amdgcn_global_load_lds((GV*)g, (LV*)l, 16, 0, 0);
}

// ---------------------------------------------------------------------------
// Fused prep: blocks 0..4095 convert x fp32->bf16 (4 el/thread);
// blocks 4096..8191 transpose the 4 weight matrices (fp32 [k][n] -> bf16 [n][k]).
__global__ void prep_kernel(const float* __restrict__ x, unsigned short* __restrict__ xb,
                            const float* __restrict__ W0, const float* __restrict__ W1,
                            const float* __restrict__ W2, const float* __restrict__ W3,
                            unsigned short* __restrict__ D0, unsigned short* __restrict__ D1,
                            unsigned short* __restrict__ D2, unsigned short* __restrict__ D3) {
    const int bid = blockIdx.x, tid = threadIdx.x;
    if (bid < 4096) {
        const int i = (bid * 256 + tid) * 4;
        const floatvec4 v = *(const floatvec4*)&x[i];
        ushort4v o;
#pragma unroll
        for (int r = 0; r < 4; r++) o[r] = f2bf(v[r]);
        *(ushort4v*)&xb[i] = o;
        return;
    }
    __shared__ float t[32][33];
    const int tcode = bid - 4096;
    const int z = tcode >> 10, rem = tcode & 1023;
    const int by = rem >> 5, bx = rem & 31;
    const int tx = tid & 31, ty = tid >> 5;  // (32,8)
    const float* W = (z == 0) ? W0 : (z == 1) ? W1 : (z == 2) ? W2 : W3;
    unsigned short* D = (z == 0) ? D0 : (z == 1) ? D1 : (z == 2) ? D2 : D3;
#pragma unroll
    for (int i = 0; i < 4; i++)
        t[ty + i * 8][tx] = W[(size_t)(by * 32 + ty + i * 8) * 1024 + bx * 32 + tx];
    __syncthreads();
#pragma unroll
    for (int i = 0; i < 4; i++)
        D[(size_t)(bx * 32 + ty + i * 8) * 1024 + by * 32 + tx] = f2bf(t[tx][ty + i * 8]);
}

// ---------------------------------------------------------------------------
// Fused QKV GEMM, BK=64: C[4096 tok][1024] = Xbf @ W{q,k,v}t^T (+bias).
// (verified R0 kernel)
__global__ __launch_bounds__(256, 3) void qkv_gemm(
    const unsigned short* __restrict__ X, const unsigned short* __restrict__ Wt,
    const float* __restrict__ bq, const float* __restrict__ bk, const float* __restrict__ bv,
    unsigned short* __restrict__ qb, unsigned short* __restrict__ kb,
    unsigned short* __restrict__ vtb)
{
    __shared__ __align__(16) unsigned short As[128 * 64];
    __shared__ __align__(16) unsigned short Bs[128 * 64];
    const int tid = threadIdx.x, lane = tid & 63, wv = tid >> 6;
    const int quad = lane >> 4, l16 = lane & 15;
    const int w = blockIdx.x >> 3;
    const int n0 = (blockIdx.x & 7) * 128;
    const int row0 = blockIdx.y * 128;
    const unsigned short* Wsel = Wt + (size_t)w * (1024 * 1024);

    const int srow = lane >> 3;
    const int qsc = ((lane & 7) ^ (lane >> 3 & 7)) * 8;
    const int fsw = l16 & 7;
    const int wm = (wv >> 1) * 64, wn = (wv & 1) * 64;

    float4v acc[4][4];
#pragma unroll
    for (int i = 0; i < 4; i++)
#pragma unroll
        for (int j = 0; j < 4; j++) acc[i][j] = (float4v){0.f, 0.f, 0.f, 0.f};

    for (int k0 = 0; k0 < 1024; k0 += 64) {
        __syncthreads();
#pragma unroll
        for (int i = 0; i < 4; i++) {
            const int c = wv * 4 + i;
            gl2lds16(X + (size_t)(row0 + c * 8 + srow) * 1024 + k0 + qsc, As + c * 512);
            gl2lds16(Wsel + (size_t)(n0 + c * 8 + srow) * 1024 + k0 + qsc, Bs + c * 512);
        }
        __syncthreads();
#pragma unroll
        for (int kc = 0; kc < 2; kc++) {
            const int sl = (((kc * 4 + quad) ^ fsw) * 8);
            short8v a[4], b[4];
#pragma unroll
            for (int mt = 0; mt < 4; mt++)
                a[mt] = *(const short8v*)&As[(wm + mt * 16 + l16) * 64 + sl];
#pragma unroll
            for (int nt = 0; nt < 4; nt++)
                b[nt] = *(const short8v*)&Bs[(wn + nt * 16 + l16) * 64 + sl];
#pragma unroll
            for (int mt = 0; mt < 4; mt++)
#pragma unroll
                for (int nt = 0; nt < 4; nt++)
                    acc[mt][nt] = __builtin_amdgcn_mfma_f32_16x16x32_bf16(a[mt], b[nt], acc[mt][nt], 0, 0, 0);
        }
    }

    const float* bias = (w == 0) ? bq : (w == 1) ? bk : bv;
    const float scl = (w == 0) ? 0.18033688011112042f : 1.0f;
#pragma unroll
    for (int nt = 0; nt < 4; nt++) {
        const int col = n0 + wn + nt * 16 + l16;
        const float bb = bias[col];
        const int h = col >> 6, hd = col & 63;
#pragma unroll
        for (int mt = 0; mt < 4; mt++) {
            const int tok0 = row0 + wm + mt * 16 + quad * 4;
            const int b_ = tok0 >> 11, s0 = tok0 & 2047;
            if (w == 2) {
                ushort4v pk;
#pragma unroll
                for (int r = 0; r < 4; r++) pk[r] = f2bf(acc[mt][nt][r] + bb);
                *(ushort4v*)&vtb[(((size_t)b_ * 16 + h) * 64 + hd) * 2048 + s0] = pk;
            } else {
                unsigned short* dst = (w == 0) ? qb : kb;
#pragma unroll
                for (int r = 0; r < 4; r++)
                    dst[(((size_t)b_ * 16 + h) * 2048 + (s0 + r)) * 64 + hd] =
                        f2bf((acc[mt][nt][r] + bb) * scl);
            }
        }
    }
}

// ---------------------------------------------------------------------------
// Flash attention, S^T formulation.
// v9 = split-KV flash-decode. Grid (32,32,2): z = KV half (1024 keys each)
//      -> 2048 blocks = 8 blocks/CU; KVBLK=64 -> LDS 16KB (8x16=128<=160);
//      VGPR ~52 @ launch_bounds(256,8) -> 32 waves/CU (2x R11 — kernel is
//      latency-bound per R2-vs-R10 evidence). Partial O (f32, ctx layout) +
//      partial L per half; combine kernel normalizes. KVBLK=64 V-tile lane
//      math == the verified K-tile pattern (granule ^= row&7). Keeps the
//      R11-verified permlane P-path + MFMA-fused rowsum (accL).
//      Fallback (gridDim.z==1, pO==null): full KV range, direct ctx write.
__global__ __launch_bounds__(256, 8) void attn_kernel(
    const unsigned short* __restrict__ qb, const unsigned short* __restrict__ kb,
    const unsigned short* __restrict__ vtb, unsigned short* __restrict__ ctxb,
    float* __restrict__ pO0, float* __restrict__ pO1,
    float* __restrict__ pL0, float* __restrict__ pL1)
{
    __shared__ __align__(16) unsigned short Kt[64 * 64];  // [key][hd]   8KB
    __shared__ __align__(16) unsigned short Vt[64 * 64];  // [hd][key]   8KB
    const int tid = threadIdx.x, lane = tid & 63, wv = tid >> 6;
    const int quad = lane >> 4, l16 = lane & 15;
    const int bh = blockIdx.x, qt = blockIdx.y;
    const int half = blockIdx.z;
    const bool partial = (gridDim.z == 2);
    const int kv0 = half << 10;
    const int kvend = partial ? (kv0 + 1024) : 2048;
    float* __restrict__ pO = half ? pO1 : pO0;
    float* __restrict__ pL = half ? pL1 : pL0;

    const size_t boff = (size_t)bh * (2048 * 64);
    const unsigned short* qp = qb + boff;
    const unsigned short* kp = kb + boff;
    const unsigned short* vp = vtb + boff;
    const int q0 = qt * 64 + wv * 16;  // 16 q-rows per wave

    // Q fragments (B operand): [q=l16][hd=quad*8..], register-resident
    short8v qf[2];
#pragma unroll
    for (int kc = 0; kc < 2; kc++)
        qf[kc] = *(const short8v*)&qp[(size_t)(q0 + l16) * 64 + kc * 32 + quad * 8];

    float4v accO[4];
#pragma unroll
    for (int ht = 0; ht < 4; ht++) accO[ht] = (float4v){0.f, 0.f, 0.f, 0.f};
    float4v accL = (float4v){0.f, 0.f, 0.f, 0.f};  // MFMA-fused row-sums

    const ushort8v onesu = (ushort8v){0x3F80, 0x3F80, 0x3F80, 0x3F80,
                                      0x3F80, 0x3F80, 0x3F80, 0x3F80};
    const short8v ones = __builtin_bit_cast(short8v, onesu);

    // staging lane mapping: chunk = 8 rows x 64 shorts (1KB); slot lane&7
    // holds data granule (lane&7)^(row&7) — verified K pattern, now both K&V.
    const int srow8 = lane >> 3;
    const int sg = ((lane & 7) ^ srow8) * 8;
    const int rsw = l16 & 7;

    // frag read bases: row r, granule g -> addr r*64 + ((g^(r&7))*8)
    const int fb0 = l16 * 64 + ((quad ^ rsw) * 8);        // granule quad
    const int fb1 = l16 * 64 + (((4 + quad) ^ rsw) * 8);  // granule 4+quad

    for (int kt = kv0; kt < kvend; kt += 64) {
        __syncthreads();
#pragma unroll
        for (int i = 0; i < 2; i++) {
            const int c = wv * 2 + i;  // chunks 0..7
            gl2lds16(kp + (size_t)(kt + c * 8 + srow8) * 64 + sg, Kt + c * 512);
            gl2lds16(vp + (size_t)(c * 8 + srow8) * 2048 + kt + sg, Vt + c * 512);
        }
        __syncthreads();

        // ---- S phase: 64 keys; 8 independent MFMAs; P -> 8 packed regs
        unsigned int pkr[4][2];
#pragma unroll
        for (int mt = 0; mt < 4; mt++) {
            const short8v a0 = *(const short8v*)&Kt[fb0 + mt * 1024];
            const short8v a1 = *(const short8v*)&Kt[fb1 + mt * 1024];
            float4v z = (float4v){0.f, 0.f, 0.f, 0.f};
            z = __builtin_amdgcn_mfma_f32_16x16x32_bf16(a0, qf[0], z, 0, 0, 0);
            z = __builtin_amdgcn_mfma_f32_16x16x32_bf16(a1, qf[1], z, 0, 0, 0);
            pkr[mt][0] = pk2bf(ex2(z[0]), ex2(z[1]));
            pkr[mt][1] = pk2bf(ex2(z[2]), ex2(z[3]));
        }

        // ---- PV phase: per 32-key group kc (0..1), A-frag via quad exchange
#pragma unroll
        for (int kc = 0; kc < 2; kc++) {
            const uint2v s0 = pl32swap(pkr[2 * kc][0], pkr[2 * kc + 1][0]);
            const uint2v s1 = pl32swap(pkr[2 * kc][1], pkr[2 * kc + 1][1]);
            const uint2v t0 = pl16swap(s0.x, s0.y);
            const uint2v t1 = pl16swap(s1.x, s1.y);
            const uint4v fu = (uint4v){t0.x, t1.x, t0.y, t1.y};
            const short8v ap = __builtin_bit_cast(short8v, fu);
            accL = __builtin_amdgcn_mfma_f32_16x16x32_bf16(ap, ones, accL, 0, 0, 0);
            const int vb = kc ? fb1 : fb0;  // V read == K read pattern
#pragma unroll
            for (int ht = 0; ht < 4; ht++) {
                const short8v bv = *(const short8v*)&Vt[vb + ht * 1024];
                accO[ht] = __builtin_amdgcn_mfma_f32_16x16x32_bf16(ap, bv, accO[ht], 0, 0, 0);
            }
        }
    }

    const int b_ = bh >> 4, h = bh & 15;
    if (partial) {
#pragma unroll
        for (int r = 0; r < 4; r++) {
            const int s = q0 + quad * 4 + r;
            float* dst = pO + ((size_t)(b_ * 2048 + s)) * 1024 + h * 64;
#pragma unroll
            for (int ht = 0; ht < 4; ht++) dst[ht * 16 + l16] = accO[ht][r];
        }
        if (l16 == 0) {
#pragma unroll
            for (int r = 0; r < 4; r++)
                pL[((size_t)b_ * 16 + h) * 2048 + q0 + quad * 4 + r] = accL[r];
        }
    } else {
#pragma unroll
        for (int r = 0; r < 4; r++) {
            const int s = q0 + quad * 4 + r;
            const float inv = 1.0f / accL[r];
#pragma unroll
            for (int ht = 0; ht < 4; ht++) {
                const int hd = ht * 16 + l16;
                ctxb[((size_t)(b_ * 2048 + s)) * 1024 + h * 64 + hd] = f2bf(accO[ht][r] * inv);
            }
        }
    }
}

// ---------------------------------------------------------------------------
// combine: ctx = (O0 + O1) / (L0 + L1), bf16. 4M floats, 4/thread.
__global__ __launch_bounds__(256) void combine_kernel(
    const float* __restrict__ pO0, const float* __restrict__ pO1,
    const float* __restrict__ pL0, const float* __restrict__ pL1,
    unsigned short* __restrict__ ctxb)
{
    const int i4 = (blockIdx.x * 256 + threadIdx.x) * 4;
    const int h = (i4 >> 6) & 15, s = (i4 >> 10) & 2047, b_ = i4 >> 21;
    const int li = (b_ * 16 + h) * 2048 + s;
    const float inv = 1.0f / (pL0[li] + pL1[li]);
    const floatvec4 o0 = *(const floatvec4*)&pO0[i4];
    const floatvec4 o1 = *(const floatvec4*)&pO1[i4];
    ushort4v o;
#pragma unroll
    for (int j = 0; j < 4; j++) o[j] = f2bf((o0[j] + o1[j]) * inv);
    *(ushort4v*)&ctxb[i4] = o;
}

// ---------------------------------------------------------------------------
// out = ctx @ Wo + bo (fp32 output). (verified R0 kernel)
__global__ __launch_bounds__(256, 2) void out_gemm(
    const unsigned short* __restrict__ ctx, const unsigned short* __restrict__ Wot,
    const float* __restrict__ bo, float* __restrict__ out)
{
    __shared__ __align__(16) unsigned short As[128 * 64];
    __shared__ __align__(16) unsigned short Bs[64 * 64];
    const int tid = threadIdx.x, lane = tid & 63, wv = tid >> 6;
    const int quad = lane >> 4, l16 = lane & 15;
    const int n0 = blockIdx.x * 64;
    const int row0 = blockIdx.y * 128;

    const int srow = lane >> 3;
    const int qsc = ((lane & 7) ^ (lane >> 3 & 7)) * 8;
    const int fsw = l16 & 7;
    const int wm = (wv & 1) * 64, wn = (wv >> 1) * 32;

    float4v acc[4][2];
#pragma unroll
    for (int i = 0; i < 4; i++)
#pragma unroll
        for (int j = 0; j < 2; j++) acc[i][j] = (float4v){0.f, 0.f, 0.f, 0.f};

    for (int k0 = 0; k0 < 1024; k0 += 64) {
        __syncthreads();
#pragma unroll
        for (int i = 0; i < 6; i++) {
            const int c = wv * 6 + i;
            if (c < 16)
                gl2lds16(ctx + (size_t)(row0 + c * 8 + srow) * 1024 + k0 + qsc, As + c * 512);
            else
                gl2lds16(Wot + (size_t)(n0 + (c - 16) * 8 + srow) * 1024 + k0 + qsc,
                         Bs + (c - 16) * 512);
        }
        __syncthreads();
#pragma unroll
        for (int kc = 0; kc < 2; kc++) {
            const int sl = (((kc * 4 + quad) ^ fsw) * 8);
            short8v a[4], b[2];
#pragma unroll
            for (int mt = 0; mt < 4; mt++)
                a[mt] = *(const short8v*)&As[(wm + mt * 16 + l16) * 64 + sl];
#pragma unroll
            for (int nt = 0; nt < 2; nt++)
                b[nt] = *(const short8v*)&Bs[(wn + nt * 16 + l16) * 64 + sl];
#pragma unroll
            for (int mt = 0; mt < 4; mt++)
#pragma unroll
                for (int nt = 0; nt < 2; nt++)
                    acc[mt][nt] = __builtin_amdgcn_mfma_f32_16x16x32_bf16(a[mt], b[nt], acc[mt][nt], 0, 0, 0);
        }
    }

#pragma unroll
    for (int nt = 0; nt < 2; nt++) {
        const int col = n0 + wn + nt * 16 + l16;
        const float bb = bo[col];
#pragma unroll
        for (int mt = 0; mt < 4; mt++) {
            const int tok0 = row0 + wm + mt * 16 + quad * 4;
#pragma unroll
            for (int r = 0; r < 4; r++)
                out[(size_t)(tok0 + r) * 1024 + col] = acc[mt][nt][r] + bb;
        }
    }
}

// ---------------------------------------------------------------------------
extern "C" void kernel_launch(void* const* d_in, const int* in_sizes, int n_in,
                              void* d_out, int out_size, void* d_ws, size_t ws_size,
                              hipStream_t stream) {
    const float* x  = (const float*)d_in[0];
    const float* Wq = (const float*)d_in[1];
    const float* bq = (const float*)d_in[2];
    const float* Wk = (const float*)d_in[3];
    const float* bk = (const float*)d_in[4];
    const float* Wv = (const float*)d_in[5];
    const float* bv = (const float*)d_in[6];
    const float* Wo = (const float*)d_in[7];
    const float* bo = (const float*)d_in[8];
    float* out = (float*)d_out;

    char* ws = (char*)d_ws;
    unsigned short* xb   = (unsigned short*)(ws);                   // 8MB; reused as ctx
    unsigned short* qbuf = (unsigned short*)(ws + (8u << 20));      // 8MB
    unsigned short* kbuf = (unsigned short*)(ws + (16u << 20));     // 8MB
    unsigned short* vtb  = (unsigned short*)(ws + (24u << 20));     // 8MB
    unsigned short* wt   = (unsigned short*)(ws + (32u << 20));     // 6MB
    unsigned short* wot  = (unsigned short*)(ws + (38u << 20));     // 2MB
    // split-KV partials: half0 O -> d_out (16MB, free until out_gemm);
    // half1 O -> ws+40MB (16MB); L0/L1 -> ws+56MB (512KB)
    float* pO0 = (float*)out;
    float* pO1 = (float*)(ws + (40u << 20));
    float* pL0 = (float*)(ws + (56u << 20));
    float* pL1 = pL0 + 65536;

    const bool split = ws_size >= ((size_t)57 << 20);

    prep_kernel<<<8192, 256, 0, stream>>>(x, xb, Wq, Wk, Wv, Wo,
                                          wt, wt + (1u << 20), wt + (2u << 20), wot);
    qkv_gemm<<<dim3(24, 32), 256, 0, stream>>>(xb, wt, bq, bk, bv, qbuf, kbuf, vtb);
    if (split) {
        attn_kernel<<<dim3(32, 32, 2), 256, 0, stream>>>(qbuf, kbuf, vtb, xb,
                                                         pO0, pO1, pL0, pL1);
        combine_kernel<<<4096, 256, 0, stream>>>(pO0, pO1, pL0, pL1, xb /*ctx*/);
    } else {
        attn_kernel<<<dim3(32, 32, 1), 256, 0, stream>>>(qbuf, kbuf, vtb, xb /*ctx*/,
                                                         nullptr, nullptr, nullptr, nullptr);
    }
    out_gemm<<<dim3(16, 32), 256, 0, stream>>>(xb, wot, bo, out);
}

// Round 13
// 192.415 us; speedup vs baseline: 1.0669x; 1.0669x over previous
//
#include <hip/hip_runtime.h>
#include <stdint.h>

typedef __attribute__((ext_vector_type(8))) short short8v;    // 8 x bf16 (raw bits)
typedef __attribute__((ext_vector_type(4))) short short4v;    // 4 x bf16
typedef __attribute__((ext_vector_type(4))) float float4v;    // MFMA C/D
typedef __attribute__((ext_vector_type(4))) unsigned short ushort4v;
typedef __attribute__((ext_vector_type(4))) float floatvec4;
typedef __attribute__((ext_vector_type(2))) unsigned int uint2v;
typedef __attribute__((ext_vector_type(4))) unsigned int uint4v;
typedef __attribute__((ext_vector_type(8))) unsigned short ushort8v;

#define DEVI __device__ __forceinline__

// fp32 -> bf16 round-to-nearest-even (finite inputs only)
DEVI unsigned short f2bf(float f) {
    unsigned int u = __builtin_bit_cast(unsigned int, f);
    u += 0x7FFFu + ((u >> 16) & 1u);
    return (unsigned short)(u >> 16);
}

// pack 2 fp32 -> 2 bf16 in one u32 (low = a)
DEVI unsigned int pk2bf(float a, float b) {
#if defined(__has_builtin) && __has_builtin(__builtin_amdgcn_cvt_pk_bf16_f32)
    auto r = __builtin_amdgcn_cvt_pk_bf16_f32(a, b);
    unsigned int u;
    __builtin_memcpy(&u, &r, 4);
    return u;
#else
    return (unsigned int)f2bf(a) | ((unsigned int)f2bf(b) << 16);
#endif
}

DEVI float ex2(float x) {
#if defined(__has_builtin) && __has_builtin(__builtin_amdgcn_exp2f)
    return __builtin_amdgcn_exp2f(x);
#else
    return __builtin_exp2f(x);
#endif
}

// permlane swaps (hardware-verified lane mapping, R1/R2/R10/R11 passed):
// P32: D[32:63] <-> S[0:31].  P16: D[16:31]<->S[0:15], D[48:63]<->S[32:47].
DEVI uint2v pl32swap(unsigned int d, unsigned int s) {
#if defined(__has_builtin) && __has_builtin(__builtin_amdgcn_permlane32_swap)
    return __builtin_amdgcn_permlane32_swap(d, s, false, false);
#else
    const int hi = (int)(threadIdx.x & 32);
    unsigned int dp = __shfl_xor(d, 32), sp = __shfl_xor(s, 32);
    return (uint2v){hi ? sp : d, hi ? s : dp};
#endif
}
DEVI uint2v pl16swap(unsigned int d, unsigned int s) {
#if defined(__has_builtin) && __has_builtin(__builtin_amdgcn_permlane16_swap)
    return __builtin_amdgcn_permlane16_swap(d, s, false, false);
#else
    const int lo = (int)(threadIdx.x & 16);
    unsigned int dp = __shfl_xor(d, 16), sp = __shfl_xor(s, 16);
    return (uint2v){lo ? sp : d, lo ? s : dp};
#endif
}

typedef __attribute__((address_space(1))) void GV;
typedef __attribute__((address_space(3))) void LV;
// async global->LDS, 16B per lane; LDS dest = wave-uniform base + lane*16
DEVI void gl2lds16(const void* g, void* l) {
    __builtin_amdgcn_global_load_lds((GV*)g, (LV*)l, 16, 0, 0);
}

// ---------------------------------------------------------------------------
// Fused prep: blocks 0..4095 convert x fp32->bf16 (4 el/thread);
// blocks 4096..8191 transpose the 4 weight matrices (fp32 [k][n] -> bf16 [n][k]).
__global__ void prep_kernel(const float* __restrict__ x, unsigned short* __restrict__ xb,
                            const float* __restrict__ W0, const float* __restrict__ W1,
                            const float* __restrict__ W2, const float* __restrict__ W3,
                            unsigned short* __restrict__ D0, unsigned short* __restrict__ D1,
                            unsigned short* __restrict__ D2, unsigned short* __restrict__ D3) {
    const int bid = blockIdx.x, tid = threadIdx.x;
    if (bid < 4096) {
        const int i = (bid * 256 + tid) * 4;
        const floatvec4 v = *(const floatvec4*)&x[i];
        ushort4v o;
#pragma unroll
        for (int r = 0; r < 4; r++) o[r] = f2bf(v[r]);
        *(ushort4v*)&xb[i] = o;
        return;
    }
    __shared__ float t[32][33];
    const int tcode = bid - 4096;
    const int z = tcode >> 10, rem = tcode & 1023;
    const int by = rem >> 5, bx = rem & 31;
    const int tx = tid & 31, ty = tid >> 5;  // (32,8)
    const float* W = (z == 0) ? W0 : (z == 1) ? W1 : (z == 2) ? W2 : W3;
    unsigned short* D = (z == 0) ? D0 : (z == 1) ? D1 : (z == 2) ? D2 : D3;
#pragma unroll
    for (int i = 0; i < 4; i++)
        t[ty + i * 8][tx] = W[(size_t)(by * 32 + ty + i * 8) * 1024 + bx * 32 + tx];
    __syncthreads();
#pragma unroll
    for (int i = 0; i < 4; i++)
        D[(size_t)(bx * 32 + ty + i * 8) * 1024 + by * 32 + tx] = f2bf(t[tx][ty + i * 8]);
}

// ---------------------------------------------------------------------------
// Fused QKV GEMM, BK=64: C[4096 tok][1024] = Xbf @ W{q,k,v}t^T (+bias).
// (verified R0 kernel; R13: launch_bounds 3 -> 4 blocks/CU occupancy test.
//  LDS 32KB x 4 = 128KB <= 160; VGPR est ~116 <= 128 cap.)
__global__ __launch_bounds__(256, 4) void qkv_gemm(
    const unsigned short* __restrict__ X, const unsigned short* __restrict__ Wt,
    const float* __restrict__ bq, const float* __restrict__ bk, const float* __restrict__ bv,
    unsigned short* __restrict__ qb, unsigned short* __restrict__ kb,
    unsigned short* __restrict__ vtb)
{
    __shared__ __align__(16) unsigned short As[128 * 64];
    __shared__ __align__(16) unsigned short Bs[128 * 64];
    const int tid = threadIdx.x, lane = tid & 63, wv = tid >> 6;
    const int quad = lane >> 4, l16 = lane & 15;
    const int w = blockIdx.x >> 3;
    const int n0 = (blockIdx.x & 7) * 128;
    const int row0 = blockIdx.y * 128;
    const unsigned short* Wsel = Wt + (size_t)w * (1024 * 1024);

    const int srow = lane >> 3;
    const int qsc = ((lane & 7) ^ (lane >> 3 & 7)) * 8;
    const int fsw = l16 & 7;
    const int wm = (wv >> 1) * 64, wn = (wv & 1) * 64;

    float4v acc[4][4];
#pragma unroll
    for (int i = 0; i < 4; i++)
#pragma unroll
        for (int j = 0; j < 4; j++) acc[i][j] = (float4v){0.f, 0.f, 0.f, 0.f};

    for (int k0 = 0; k0 < 1024; k0 += 64) {
        __syncthreads();
#pragma unroll
        for (int i = 0; i < 4; i++) {
            const int c = wv * 4 + i;
            gl2lds16(X + (size_t)(row0 + c * 8 + srow) * 1024 + k0 + qsc, As + c * 512);
            gl2lds16(Wsel + (size_t)(n0 + c * 8 + srow) * 1024 + k0 + qsc, Bs + c * 512);
        }
        __syncthreads();
#pragma unroll
        for (int kc = 0; kc < 2; kc++) {
            const int sl = (((kc * 4 + quad) ^ fsw) * 8);
            short8v a[4], b[4];
#pragma unroll
            for (int mt = 0; mt < 4; mt++)
                a[mt] = *(const short8v*)&As[(wm + mt * 16 + l16) * 64 + sl];
#pragma unroll
            for (int nt = 0; nt < 4; nt++)
                b[nt] = *(const short8v*)&Bs[(wn + nt * 16 + l16) * 64 + sl];
#pragma unroll
            for (int mt = 0; mt < 4; mt++)
#pragma unroll
                for (int nt = 0; nt < 4; nt++)
                    acc[mt][nt] = __builtin_amdgcn_mfma_f32_16x16x32_bf16(a[mt], b[nt], acc[mt][nt], 0, 0, 0);
        }
    }

    const float* bias = (w == 0) ? bq : (w == 1) ? bk : bv;
    const float scl = (w == 0) ? 0.18033688011112042f : 1.0f;
#pragma unroll
    for (int nt = 0; nt < 4; nt++) {
        const int col = n0 + wn + nt * 16 + l16;
        const float bb = bias[col];
        const int h = col >> 6, hd = col & 63;
#pragma unroll
        for (int mt = 0; mt < 4; mt++) {
            const int tok0 = row0 + wm + mt * 16 + quad * 4;
            const int b_ = tok0 >> 11, s0 = tok0 & 2047;
            if (w == 2) {
                ushort4v pk;
#pragma unroll
                for (int r = 0; r < 4; r++) pk[r] = f2bf(acc[mt][nt][r] + bb);
                *(ushort4v*)&vtb[(((size_t)b_ * 16 + h) * 64 + hd) * 2048 + s0] = pk;
            } else {
                unsigned short* dst = (w == 0) ? qb : kb;
#pragma unroll
                for (int r = 0; r < 4; r++)
                    dst[(((size_t)b_ * 16 + h) * 2048 + (s0 + r)) * 64 + hd] =
                        f2bf((acc[mt][nt][r] + bb) * scl);
            }
        }
    }
}

// ---------------------------------------------------------------------------
// Flash attention, S^T formulation.
// v8 (R11-verified, session-best): permlane in-register P, 32KB LDS,
// 4 blocks/CU, 16 q/wave, grid (32,32), MFMA-fused row-sum (accL).
__global__ __launch_bounds__(256, 4) void attn_kernel(
    const unsigned short* __restrict__ qb, const unsigned short* __restrict__ kb,
    const unsigned short* __restrict__ vtb, unsigned short* __restrict__ ctxb)
{
    __shared__ __align__(16) unsigned short Kt[128 * 64];
    __shared__ __align__(16) unsigned short Vt[64 * 128];
    const int tid = threadIdx.x, lane = tid & 63, wv = tid >> 6;
    const int quad = lane >> 4, l16 = lane & 15;
    const int bh = blockIdx.x, qt = blockIdx.y;
    const size_t boff = (size_t)bh * (2048 * 64);
    const unsigned short* qp = qb + boff;
    const unsigned short* kp = kb + boff;
    const unsigned short* vp = vtb + boff;
    const int q0 = qt * 64 + wv * 16;  // 16 q-rows per wave

    // Q fragments (B operand): [q=l16][hd=quad*8..], register-resident
    short8v qf[2];
#pragma unroll
    for (int kc = 0; kc < 2; kc++)
        qf[kc] = *(const short8v*)&qp[(size_t)(q0 + l16) * 64 + kc * 32 + quad * 8];

    float4v accO[4];
#pragma unroll
    for (int ht = 0; ht < 4; ht++) accO[ht] = (float4v){0.f, 0.f, 0.f, 0.f};
    float4v accL = (float4v){0.f, 0.f, 0.f, 0.f};  // MFMA-fused row-sums

    // all-ones bf16 B-operand (any layout of all-ones is all-ones)
    const ushort8v onesu = (ushort8v){0x3F80, 0x3F80, 0x3F80, 0x3F80,
                                      0x3F80, 0x3F80, 0x3F80, 0x3F80};
    const short8v ones = __builtin_bit_cast(short8v, onesu);

    // staging lane mapping (verified R0)
    const int krow = lane >> 3;
    const int kg = (lane & 7) ^ (lane >> 3);
    const int vrow = lane >> 4;
    const int rsw = l16 & 7;

    // Kt A-frag read bases (row=key=mt*16+l16)
    const int ktb0 = l16 * 64 + ((quad ^ rsw) * 8);
    const int ktb1 = l16 * 64 + (((4 + quad) ^ rsw) * 8);
    // Vt B-frag read base: granule (kc*4+quad) ^ l16
    const int vrb = l16 * 128 + ((quad ^ (l16 & 3)) * 8);
    const int l12e = (l16 & 12) * 8;

    for (int kt0 = 0; kt0 < 2048; kt0 += 128) {
        __syncthreads();
#pragma unroll
        for (int i = 0; i < 4; i++) {
            const int c = wv * 4 + i;
            gl2lds16(kp + (size_t)(kt0 + c * 8 + krow) * 64 + kg * 8, Kt + c * 512);
            const int vr = c * 4 + vrow;
            const int vg = (lane & 15) ^ (vr & 15);
            gl2lds16(vp + (size_t)vr * 2048 + kt0 + vg * 8, Vt + c * 512);
        }
        __syncthreads();

        // ---- S phase: all 128 keys; 16 independent MFMAs; P -> 16 packed regs
        unsigned int pkr[8][2];
#pragma unroll
        for (int mt = 0; mt < 8; mt++) {
            const short8v a0 = *(const short8v*)&Kt[ktb0 + mt * 1024];
            const short8v a1 = *(const short8v*)&Kt[ktb1 + mt * 1024];
            float4v z = (float4v){0.f, 0.f, 0.f, 0.f};
            z = __builtin_amdgcn_mfma_f32_16x16x32_bf16(a0, qf[0], z, 0, 0, 0);
            z = __builtin_amdgcn_mfma_f32_16x16x32_bf16(a1, qf[1], z, 0, 0, 0);
            pkr[mt][0] = pk2bf(ex2(z[0]), ex2(z[1]));
            pkr[mt][1] = pk2bf(ex2(z[2]), ex2(z[3]));
        }

        // ---- PV phase: per 32-key group kc, assemble A-frag in-register
        // (quad exchange: 2x pl32swap + 2x pl16swap; mapping verified R1/R2)
#pragma unroll
        for (int kc = 0; kc < 4; kc++) {
            const int roff = (kc * 32) ^ l12e;
            short8v bvv[4];
#pragma unroll
            for (int ht = 0; ht < 4; ht++)
                bvv[ht] = *(const short8v*)&Vt[vrb + roff + ht * 2048];
            const uint2v s0 = pl32swap(pkr[2 * kc][0], pkr[2 * kc + 1][0]);
            const uint2v s1 = pl32swap(pkr[2 * kc][1], pkr[2 * kc + 1][1]);
            const uint2v t0 = pl16swap(s0.x, s0.y);  // {keys+0,1 ; keys+4,5}
            const uint2v t1 = pl16swap(s1.x, s1.y);  // {keys+2,3 ; keys+6,7}
            const uint4v fu = (uint4v){t0.x, t1.x, t0.y, t1.y};
            const short8v ap = __builtin_bit_cast(short8v, fu);
            accL = __builtin_amdgcn_mfma_f32_16x16x32_bf16(ap, ones, accL, 0, 0, 0);
#pragma unroll
            for (int ht = 0; ht < 4; ht++)
                accO[ht] = __builtin_amdgcn_mfma_f32_16x16x32_bf16(ap, bvv[ht], accO[ht], 0, 0, 0);
        }
    }

    // accL[r] = sum over all 2048 keys of P[query = q0+quad*4+r] (same value
    // in every l16 lane) — no cross-lane reduction needed.
    const int b_ = bh >> 4, h = bh & 15;
#pragma unroll
    for (int r = 0; r < 4; r++) {
        const int s = q0 + quad * 4 + r;
        const float inv = 1.0f / accL[r];
#pragma unroll
        for (int ht = 0; ht < 4; ht++) {
            const int hd = ht * 16 + l16;
            ctxb[((size_t)(b_ * 2048 + s)) * 1024 + h * 64 + hd] = f2bf(accO[ht][r] * inv);
        }
    }
}

// ---------------------------------------------------------------------------
// out = ctx @ Wo + bo (fp32 output). 128m x 64n tile, BK=64 (qkv-style
// staging). Wave = 64m x 32n, 16 MFMA per barrier-pair, 16 k-iters.
// Grid (16,32) = 512. (verified R0 kernel; R13: launch_bounds 2 -> 3
// blocks/CU occupancy test. LDS 24KB x 3 = 72KB; VGPR est ~70.)
__global__ __launch_bounds__(256, 3) void out_gemm(
    const unsigned short* __restrict__ ctx, const unsigned short* __restrict__ Wot,
    const float* __restrict__ bo, float* __restrict__ out)
{
    __shared__ __align__(16) unsigned short As[128 * 64];
    __shared__ __align__(16) unsigned short Bs[64 * 64];
    const int tid = threadIdx.x, lane = tid & 63, wv = tid >> 6;
    const int quad = lane >> 4, l16 = lane & 15;
    const int n0 = blockIdx.x * 64;
    const int row0 = blockIdx.y * 128;

    const int srow = lane >> 3;
    const int qsc = ((lane & 7) ^ (lane >> 3 & 7)) * 8;
    const int fsw = l16 & 7;
    const int wm = (wv & 1) * 64, wn = (wv >> 1) * 32;

    float4v acc[4][2];
#pragma unroll
    for (int i = 0; i < 4; i++)
#pragma unroll
        for (int j = 0; j < 2; j++) acc[i][j] = (float4v){0.f, 0.f, 0.f, 0.f};

    for (int k0 = 0; k0 < 1024; k0 += 64) {
        __syncthreads();
#pragma unroll
        for (int i = 0; i < 6; i++) {
            const int c = wv * 6 + i;  // 0..23: 16 As chunks then 8 Bs chunks
            if (c < 16)
                gl2lds16(ctx + (size_t)(row0 + c * 8 + srow) * 1024 + k0 + qsc, As + c * 512);
            else
                gl2lds16(Wot + (size_t)(n0 + (c - 16) * 8 + srow) * 1024 + k0 + qsc,
                         Bs + (c - 16) * 512);
        }
        __syncthreads();
#pragma unroll
        for (int kc = 0; kc < 2; kc++) {
            const int sl = (((kc * 4 + quad) ^ fsw) * 8);
            short8v a[4], b[2];
#pragma unroll
            for (int mt = 0; mt < 4; mt++)
                a[mt] = *(const short8v*)&As[(wm + mt * 16 + l16) * 64 + sl];
#pragma unroll
            for (int nt = 0; nt < 2; nt++)
                b[nt] = *(const short8v*)&Bs[(wn + nt * 16 + l16) * 64 + sl];
#pragma unroll
            for (int mt = 0; mt < 4; mt++)
#pragma unroll
                for (int nt = 0; nt < 2; nt++)
                    acc[mt][nt] = __builtin_amdgcn_mfma_f32_16x16x32_bf16(a[mt], b[nt], acc[mt][nt], 0, 0, 0);
        }
    }

#pragma unroll
    for (int nt = 0; nt < 2; nt++) {
        const int col = n0 + wn + nt * 16 + l16;
        const float bb = bo[col];
#pragma unroll
        for (int mt = 0; mt < 4; mt++) {
            const int tok0 = row0 + wm + mt * 16 + quad * 4;
#pragma unroll
            for (int r = 0; r < 4; r++)
                out[(size_t)(tok0 + r) * 1024 + col] = acc[mt][nt][r] + bb;
        }
    }
}

// ---------------------------------------------------------------------------
extern "C" void kernel_launch(void* const* d_in, const int* in_sizes, int n_in,
                              void* d_out, int out_size, void* d_ws, size_t ws_size,
                              hipStream_t stream) {
    const float* x  = (const float*)d_in[0];
    const float* Wq = (const float*)d_in[1];
    const float* bq = (const float*)d_in[2];
    const float* Wk = (const float*)d_in[3];
    const float* bk = (const float*)d_in[4];
    const float* Wv = (const float*)d_in[5];
    const float* bv = (const float*)d_in[6];
    const float* Wo = (const float*)d_in[7];
    const float* bo = (const float*)d_in[8];
    float* out = (float*)d_out;

    char* ws = (char*)d_ws;
    unsigned short* xb   = (unsigned short*)(ws);                   // 8MB; reused as ctx
    unsigned short* qbuf = (unsigned short*)(ws + (8u << 20));      // 8MB
    unsigned short* kbuf = (unsigned short*)(ws + (16u << 20));     // 8MB
    unsigned short* vtb  = (unsigned short*)(ws + (24u << 20));     // 8MB
    unsigned short* wt   = (unsigned short*)(ws + (32u << 20));     // 6MB
    unsigned short* wot  = (unsigned short*)(ws + (38u << 20));     // 2MB

    prep_kernel<<<8192, 256, 0, stream>>>(x, xb, Wq, Wk, Wv, Wo,
                                          wt, wt + (1u << 20), wt + (2u << 20), wot);
    qkv_gemm<<<dim3(24, 32), 256, 0, stream>>>(xb, wt, bq, bk, bv, qbuf, kbuf, vtb);
    attn_kernel<<<dim3(32, 32), 256, 0, stream>>>(qbuf, kbuf, vtb, xb /*ctx*/);
    out_gemm<<<dim3(16, 32), 256, 0, stream>>>(xb, wot, bo, out);
}

// Round 14
// 187.141 us; speedup vs baseline: 1.0970x; 1.0282x over previous
//
#include <hip/hip_runtime.h>
#include <stdint.h>

typedef __attribute__((ext_vector_type(8))) short short8v;    // 8 x bf16 (raw bits)
typedef __attribute__((ext_vector_type(4))) short short4v;    // 4 x bf16
typedef __attribute__((ext_vector_type(4))) float float4v;    // MFMA C/D
typedef __attribute__((ext_vector_type(4))) unsigned short ushort4v;
typedef __attribute__((ext_vector_type(4))) float floatvec4;
typedef __attribute__((ext_vector_type(2))) unsigned int uint2v;
typedef __attribute__((ext_vector_type(4))) unsigned int uint4v;
typedef __attribute__((ext_vector_type(8))) unsigned short ushort8v;

#define DEVI __device__ __forceinline__

// fp32 -> bf16 round-to-nearest-even (finite inputs only)
DEVI unsigned short f2bf(float f) {
    unsigned int u = __builtin_bit_cast(unsigned int, f);
    u += 0x7FFFu + ((u >> 16) & 1u);
    return (unsigned short)(u >> 16);
}

// pack 2 fp32 -> 2 bf16 in one u32 (low = a)
DEVI unsigned int pk2bf(float a, float b) {
#if defined(__has_builtin) && __has_builtin(__builtin_amdgcn_cvt_pk_bf16_f32)
    auto r = __builtin_amdgcn_cvt_pk_bf16_f32(a, b);
    unsigned int u;
    __builtin_memcpy(&u, &r, 4);
    return u;
#else
    return (unsigned int)f2bf(a) | ((unsigned int)f2bf(b) << 16);
#endif
}

DEVI float ex2(float x) {
#if defined(__has_builtin) && __has_builtin(__builtin_amdgcn_exp2f)
    return __builtin_amdgcn_exp2f(x);
#else
    return __builtin_exp2f(x);
#endif
}

// permlane swaps (hardware-verified lane mapping, R1/R2/R10/R11 passed):
// P32: D[32:63] <-> S[0:31].  P16: D[16:31]<->S[0:15], D[48:63]<->S[32:47].
DEVI uint2v pl32swap(unsigned int d, unsigned int s) {
#if defined(__has_builtin) && __has_builtin(__builtin_amdgcn_permlane32_swap)
    return __builtin_amdgcn_permlane32_swap(d, s, false, false);
#else
    const int hi = (int)(threadIdx.x & 32);
    unsigned int dp = __shfl_xor(d, 32), sp = __shfl_xor(s, 32);
    return (uint2v){hi ? sp : d, hi ? s : dp};
#endif
}
DEVI uint2v pl16swap(unsigned int d, unsigned int s) {
#if defined(__has_builtin) && __has_builtin(__builtin_amdgcn_permlane16_swap)
    return __builtin_amdgcn_permlane16_swap(d, s, false, false);
#else
    const int lo = (int)(threadIdx.x & 16);
    unsigned int dp = __shfl_xor(d, 16), sp = __shfl_xor(s, 16);
    return (uint2v){lo ? sp : d, lo ? s : dp};
#endif
}

typedef __attribute__((address_space(1))) void GV;
typedef __attribute__((address_space(3))) void LV;
// async global->LDS, 16B per lane; LDS dest = wave-uniform base + lane*16
DEVI void gl2lds16(const void* g, void* l) {
    __builtin_amdgcn_global_load_lds((GV*)g, (LV*)l, 16, 0, 0);
}

// ---------------------------------------------------------------------------
// Fused prep: blocks 0..4095 convert x fp32->bf16 (4 el/thread);
// blocks 4096..8191 transpose the 4 weight matrices (fp32 [k][n] -> bf16 [n][k]).
__global__ void prep_kernel(const float* __restrict__ x, unsigned short* __restrict__ xb,
                            const float* __restrict__ W0, const float* __restrict__ W1,
                            const float* __restrict__ W2, const float* __restrict__ W3,
                            unsigned short* __restrict__ D0, unsigned short* __restrict__ D1,
                            unsigned short* __restrict__ D2, unsigned short* __restrict__ D3) {
    const int bid = blockIdx.x, tid = threadIdx.x;
    if (bid < 4096) {
        const int i = (bid * 256 + tid) * 4;
        const floatvec4 v = *(const floatvec4*)&x[i];
        ushort4v o;
#pragma unroll
        for (int r = 0; r < 4; r++) o[r] = f2bf(v[r]);
        *(ushort4v*)&xb[i] = o;
        return;
    }
    __shared__ float t[32][33];
    const int tcode = bid - 4096;
    const int z = tcode >> 10, rem = tcode & 1023;
    const int by = rem >> 5, bx = rem & 31;
    const int tx = tid & 31, ty = tid >> 5;  // (32,8)
    const float* W = (z == 0) ? W0 : (z == 1) ? W1 : (z == 2) ? W2 : W3;
    unsigned short* D = (z == 0) ? D0 : (z == 1) ? D1 : (z == 2) ? D2 : D3;
#pragma unroll
    for (int i = 0; i < 4; i++)
        t[ty + i * 8][tx] = W[(size_t)(by * 32 + ty + i * 8) * 1024 + bx * 32 + tx];
    __syncthreads();
#pragma unroll
    for (int i = 0; i < 4; i++)
        D[(size_t)(bx * 32 + ty + i * 8) * 1024 + by * 32 + tx] = f2bf(t[tx][ty + i * 8]);
}

// ---------------------------------------------------------------------------
// Fused QKV GEMM, BK=64: C[4096 tok][1024] = Xbf @ W{q,k,v}t^T (+bias).
// (verified R0 kernel; launch_bounds(256,3) is the measured optimum —
//  R13's (256,4) cost ~5us via VGPR squeeze)
__global__ __launch_bounds__(256, 3) void qkv_gemm(
    const unsigned short* __restrict__ X, const unsigned short* __restrict__ Wt,
    const float* __restrict__ bq, const float* __restrict__ bk, const float* __restrict__ bv,
    unsigned short* __restrict__ qb, unsigned short* __restrict__ kb,
    unsigned short* __restrict__ vtb)
{
    __shared__ __align__(16) unsigned short As[128 * 64];
    __shared__ __align__(16) unsigned short Bs[128 * 64];
    const int tid = threadIdx.x, lane = tid & 63, wv = tid >> 6;
    const int quad = lane >> 4, l16 = lane & 15;
    const int w = blockIdx.x >> 3;
    const int n0 = (blockIdx.x & 7) * 128;
    const int row0 = blockIdx.y * 128;
    const unsigned short* Wsel = Wt + (size_t)w * (1024 * 1024);

    const int srow = lane >> 3;
    const int qsc = ((lane & 7) ^ (lane >> 3 & 7)) * 8;
    const int fsw = l16 & 7;
    const int wm = (wv >> 1) * 64, wn = (wv & 1) * 64;

    float4v acc[4][4];
#pragma unroll
    for (int i = 0; i < 4; i++)
#pragma unroll
        for (int j = 0; j < 4; j++) acc[i][j] = (float4v){0.f, 0.f, 0.f, 0.f};

    for (int k0 = 0; k0 < 1024; k0 += 64) {
        __syncthreads();
#pragma unroll
        for (int i = 0; i < 4; i++) {
            const int c = wv * 4 + i;
            gl2lds16(X + (size_t)(row0 + c * 8 + srow) * 1024 + k0 + qsc, As + c * 512);
            gl2lds16(Wsel + (size_t)(n0 + c * 8 + srow) * 1024 + k0 + qsc, Bs + c * 512);
        }
        __syncthreads();
#pragma unroll
        for (int kc = 0; kc < 2; kc++) {
            const int sl = (((kc * 4 + quad) ^ fsw) * 8);
            short8v a[4], b[4];
#pragma unroll
            for (int mt = 0; mt < 4; mt++)
                a[mt] = *(const short8v*)&As[(wm + mt * 16 + l16) * 64 + sl];
#pragma unroll
            for (int nt = 0; nt < 4; nt++)
                b[nt] = *(const short8v*)&Bs[(wn + nt * 16 + l16) * 64 + sl];
#pragma unroll
            for (int mt = 0; mt < 4; mt++)
#pragma unroll
                for (int nt = 0; nt < 4; nt++)
                    acc[mt][nt] = __builtin_amdgcn_mfma_f32_16x16x32_bf16(a[mt], b[nt], acc[mt][nt], 0, 0, 0);
        }
    }

    const float* bias = (w == 0) ? bq : (w == 1) ? bk : bv;
    const float scl = (w == 0) ? 0.18033688011112042f : 1.0f;
#pragma unroll
    for (int nt = 0; nt < 4; nt++) {
        const int col = n0 + wn + nt * 16 + l16;
        const float bb = bias[col];
        const int h = col >> 6, hd = col & 63;
#pragma unroll
        for (int mt = 0; mt < 4; mt++) {
            const int tok0 = row0 + wm + mt * 16 + quad * 4;
            const int b_ = tok0 >> 11, s0 = tok0 & 2047;
            if (w == 2) {
                ushort4v pk;
#pragma unroll
                for (int r = 0; r < 4; r++) pk[r] = f2bf(acc[mt][nt][r] + bb);
                *(ushort4v*)&vtb[(((size_t)b_ * 16 + h) * 64 + hd) * 2048 + s0] = pk;
            } else {
                unsigned short* dst = (w == 0) ? qb : kb;
#pragma unroll
                for (int r = 0; r < 4; r++)
                    dst[(((size_t)b_ * 16 + h) * 2048 + (s0 + r)) * 64 + hd] =
                        f2bf((acc[mt][nt][r] + bb) * scl);
            }
        }
    }
}

// ---------------------------------------------------------------------------
// Flash attention, S^T formulation.
// v8 (R11-verified, session-best total 187.6us): permlane in-register P,
// 32KB LDS, 4 blocks/CU, 16 q/wave, grid (32,32), MFMA-fused row-sum (accL).
__global__ __launch_bounds__(256, 4) void attn_kernel(
    const unsigned short* __restrict__ qb, const unsigned short* __restrict__ kb,
    const unsigned short* __restrict__ vtb, unsigned short* __restrict__ ctxb)
{
    __shared__ __align__(16) unsigned short Kt[128 * 64];
    __shared__ __align__(16) unsigned short Vt[64 * 128];
    const int tid = threadIdx.x, lane = tid & 63, wv = tid >> 6;
    const int quad = lane >> 4, l16 = lane & 15;
    const int bh = blockIdx.x, qt = blockIdx.y;
    const size_t boff = (size_t)bh * (2048 * 64);
    const unsigned short* qp = qb + boff;
    const unsigned short* kp = kb + boff;
    const unsigned short* vp = vtb + boff;
    const int q0 = qt * 64 + wv * 16;  // 16 q-rows per wave

    // Q fragments (B operand): [q=l16][hd=quad*8..], register-resident
    short8v qf[2];
#pragma unroll
    for (int kc = 0; kc < 2; kc++)
        qf[kc] = *(const short8v*)&qp[(size_t)(q0 + l16) * 64 + kc * 32 + quad * 8];

    float4v accO[4];
#pragma unroll
    for (int ht = 0; ht < 4; ht++) accO[ht] = (float4v){0.f, 0.f, 0.f, 0.f};
    float4v accL = (float4v){0.f, 0.f, 0.f, 0.f};  // MFMA-fused row-sums

    // all-ones bf16 B-operand (any layout of all-ones is all-ones)
    const ushort8v onesu = (ushort8v){0x3F80, 0x3F80, 0x3F80, 0x3F80,
                                      0x3F80, 0x3F80, 0x3F80, 0x3F80};
    const short8v ones = __builtin_bit_cast(short8v, onesu);

    // staging lane mapping (verified R0)
    const int krow = lane >> 3;
    const int kg = (lane & 7) ^ (lane >> 3);
    const int vrow = lane >> 4;
    const int rsw = l16 & 7;

    // Kt A-frag read bases (row=key=mt*16+l16)
    const int ktb0 = l16 * 64 + ((quad ^ rsw) * 8);
    const int ktb1 = l16 * 64 + (((4 + quad) ^ rsw) * 8);
    // Vt B-frag read base: granule (kc*4+quad) ^ l16
    const int vrb = l16 * 128 + ((quad ^ (l16 & 3)) * 8);
    const int l12e = (l16 & 12) * 8;

    for (int kt0 = 0; kt0 < 2048; kt0 += 128) {
        __syncthreads();
#pragma unroll
        for (int i = 0; i < 4; i++) {
            const int c = wv * 4 + i;
            gl2lds16(kp + (size_t)(kt0 + c * 8 + krow) * 64 + kg * 8, Kt + c * 512);
            const int vr = c * 4 + vrow;
            const int vg = (lane & 15) ^ (vr & 15);
            gl2lds16(vp + (size_t)vr * 2048 + kt0 + vg * 8, Vt + c * 512);
        }
        __syncthreads();

        // ---- S phase: all 128 keys; 16 independent MFMAs; P -> 16 packed regs
        unsigned int pkr[8][2];
#pragma unroll
        for (int mt = 0; mt < 8; mt++) {
            const short8v a0 = *(const short8v*)&Kt[ktb0 + mt * 1024];
            const short8v a1 = *(const short8v*)&Kt[ktb1 + mt * 1024];
            float4v z = (float4v){0.f, 0.f, 0.f, 0.f};
            z = __builtin_amdgcn_mfma_f32_16x16x32_bf16(a0, qf[0], z, 0, 0, 0);
            z = __builtin_amdgcn_mfma_f32_16x16x32_bf16(a1, qf[1], z, 0, 0, 0);
            pkr[mt][0] = pk2bf(ex2(z[0]), ex2(z[1]));
            pkr[mt][1] = pk2bf(ex2(z[2]), ex2(z[3]));
        }

        // ---- PV phase: per 32-key group kc, assemble A-frag in-register
        // (quad exchange: 2x pl32swap + 2x pl16swap; mapping verified R1/R2)
#pragma unroll
        for (int kc = 0; kc < 4; kc++) {
            const int roff = (kc * 32) ^ l12e;
            short8v bvv[4];
#pragma unroll
            for (int ht = 0; ht < 4; ht++)
                bvv[ht] = *(const short8v*)&Vt[vrb + roff + ht * 2048];
            const uint2v s0 = pl32swap(pkr[2 * kc][0], pkr[2 * kc + 1][0]);
            const uint2v s1 = pl32swap(pkr[2 * kc][1], pkr[2 * kc + 1][1]);
            const uint2v t0 = pl16swap(s0.x, s0.y);  // {keys+0,1 ; keys+4,5}
            const uint2v t1 = pl16swap(s1.x, s1.y);  // {keys+2,3 ; keys+6,7}
            const uint4v fu = (uint4v){t0.x, t1.x, t0.y, t1.y};
            const short8v ap = __builtin_bit_cast(short8v, fu);
            accL = __builtin_amdgcn_mfma_f32_16x16x32_bf16(ap, ones, accL, 0, 0, 0);
#pragma unroll
            for (int ht = 0; ht < 4; ht++)
                accO[ht] = __builtin_amdgcn_mfma_f32_16x16x32_bf16(ap, bvv[ht], accO[ht], 0, 0, 0);
        }
    }

    // accL[r] = sum over all 2048 keys of P[query = q0+quad*4+r] (same value
    // in every l16 lane) — no cross-lane reduction needed.
    const int b_ = bh >> 4, h = bh & 15;
#pragma unroll
    for (int r = 0; r < 4; r++) {
        const int s = q0 + quad * 4 + r;
        const float inv = 1.0f / accL[r];
#pragma unroll
        for (int ht = 0; ht < 4; ht++) {
            const int hd = ht * 16 + l16;
            ctxb[((size_t)(b_ * 2048 + s)) * 1024 + h * 64 + hd] = f2bf(accO[ht][r] * inv);
        }
    }
}

// ---------------------------------------------------------------------------
// out = ctx @ Wo + bo (fp32 output). 128m x 64n tile, BK=64 (qkv-style
// staging). Wave = 64m x 32n, 16 MFMA per barrier-pair, 16 k-iters.
// Grid (16,32) = 512 -> 2 blocks/CU. (verified R0 kernel; (256,2) is the
// measured optimum)
__global__ __launch_bounds__(256, 2) void out_gemm(
    const unsigned short* __restrict__ ctx, const unsigned short* __restrict__ Wot,
    const float* __restrict__ bo, float* __restrict__ out)
{
    __shared__ __align__(16) unsigned short As[128 * 64];
    __shared__ __align__(16) unsigned short Bs[64 * 64];
    const int tid = threadIdx.x, lane = tid & 63, wv = tid >> 6;
    const int quad = lane >> 4, l16 = lane & 15;
    const int n0 = blockIdx.x * 64;
    const int row0 = blockIdx.y * 128;

    const int srow = lane >> 3;
    const int qsc = ((lane & 7) ^ (lane >> 3 & 7)) * 8;
    const int fsw = l16 & 7;
    const int wm = (wv & 1) * 64, wn = (wv >> 1) * 32;

    float4v acc[4][2];
#pragma unroll
    for (int i = 0; i < 4; i++)
#pragma unroll
        for (int j = 0; j < 2; j++) acc[i][j] = (float4v){0.f, 0.f, 0.f, 0.f};

    for (int k0 = 0; k0 < 1024; k0 += 64) {
        __syncthreads();
#pragma unroll
        for (int i = 0; i < 6; i++) {
            const int c = wv * 6 + i;  // 0..23: 16 As chunks then 8 Bs chunks
            if (c < 16)
                gl2lds16(ctx + (size_t)(row0 + c * 8 + srow) * 1024 + k0 + qsc, As + c * 512);
            else
                gl2lds16(Wot + (size_t)(n0 + (c - 16) * 8 + srow) * 1024 + k0 + qsc,
                         Bs + (c - 16) * 512);
        }
        __syncthreads();
#pragma unroll
        for (int kc = 0; kc < 2; kc++) {
            const int sl = (((kc * 4 + quad) ^ fsw) * 8);
            short8v a[4], b[2];
#pragma unroll
            for (int mt = 0; mt < 4; mt++)
                a[mt] = *(const short8v*)&As[(wm + mt * 16 + l16) * 64 + sl];
#pragma unroll
            for (int nt = 0; nt < 2; nt++)
                b[nt] = *(const short8v*)&Bs[(wn + nt * 16 + l16) * 64 + sl];
#pragma unroll
            for (int mt = 0; mt < 4; mt++)
#pragma unroll
                for (int nt = 0; nt < 2; nt++)
                    acc[mt][nt] = __builtin_amdgcn_mfma_f32_16x16x32_bf16(a[mt], b[nt], acc[mt][nt], 0, 0, 0);
        }
    }

#pragma unroll
    for (int nt = 0; nt < 2; nt++) {
        const int col = n0 + wn + nt * 16 + l16;
        const float bb = bo[col];
#pragma unroll
        for (int mt = 0; mt < 4; mt++) {
            const int tok0 = row0 + wm + mt * 16 + quad * 4;
#pragma unroll
            for (int r = 0; r < 4; r++)
                out[(size_t)(tok0 + r) * 1024 + col] = acc[mt][nt][r] + bb;
        }
    }
}

// ---------------------------------------------------------------------------
extern "C" void kernel_launch(void* const* d_in, const int* in_sizes, int n_in,
                              void* d_out, int out_size, void* d_ws, size_t ws_size,
                              hipStream_t stream) {
    const float* x  = (const float*)d_in[0];
    const float* Wq = (const float*)d_in[1];
    const float* bq = (const float*)d_in[2];
    const float* Wk = (const float*)d_in[3];
    const float* bk = (const float*)d_in[4];
    const float* Wv = (const float*)d_in[5];
    const float* bv = (const float*)d_in[6];
    const float* Wo = (const float*)d_in[7];
    const float* bo = (const float*)d_in[8];
    float* out = (float*)d_out;

    char* ws = (char*)d_ws;
    unsigned short* xb   = (unsigned short*)(ws);                   // 8MB; reused as ctx
    unsigned short* qbuf = (unsigned short*)(ws + (8u << 20));      // 8MB
    unsigned short* kbuf = (unsigned short*)(ws + (16u << 20));     // 8MB
    unsigned short* vtb  = (unsigned short*)(ws + (24u << 20));     // 8MB
    unsigned short* wt   = (unsigned short*)(ws + (32u << 20));     // 6MB
    unsigned short* wot  = (unsigned short*)(ws + (38u << 20));     // 2MB

    prep_kernel<<<8192, 256, 0, stream>>>(x, xb, Wq, Wk, Wv, Wo,
                                          wt, wt + (1u << 20), wt + (2u << 20), wot);
    qkv_gemm<<<dim3(24, 32), 256, 0, stream>>>(xb, wt, bq, bk, bv, qbuf, kbuf, vtb);
    attn_kernel<<<dim3(32, 32), 256, 0, stream>>>(qbuf, kbuf, vtb, xb /*ctx*/);
    out_gemm<<<dim3(16, 32), 256, 0, stream>>>(xb, wot, bo, out);
}